// Round 13
// baseline (169.888 us; speedup 1.0000x reference)
//
#include <hip/hip_runtime.h>
#include <math.h>

#define SLOPE  0.2f
#define NB     32
#define LEN    512
#define LATENT 64
#define HID    64
#define IN_DIM 129
#define TROWS  514
#define NTOT   (NB * LEN)      // 16384

typedef __attribute__((ext_vector_type(8)))  short bf16x8;
typedef __attribute__((ext_vector_type(16))) float f32x16;
typedef __attribute__((ext_vector_type(4)))  float f32x4;

struct alignas(8)  US4 { unsigned short x, y, z, w; };
struct alignas(16) US8 { unsigned short s[8]; };

// round-to-nearest bf16 split: v = hi + lo + O(2^-18 v)
__device__ inline void bsplit(float v, unsigned short& hi, unsigned short& lo) {
    unsigned int u  = __builtin_bit_cast(unsigned int, v);
    unsigned int hb = (u + 0x7fffu + ((u >> 16) & 1u)) >> 16;
    hi = (unsigned short)hb;
    float fh = __builtin_bit_cast(float, hb << 16);
    float r  = v - fh;                      // exact (Sterbenz)
    unsigned int u2 = __builtin_bit_cast(unsigned int, r);
    lo = (unsigned short)((u2 + 0x7fffu + ((u2 >> 16) & 1u)) >> 16);
}

// pre-pass (512 blocks x 256): write-coalesced W1f fragments + epilogue tables.
//   t<131072: W1f[l][i][ks][part][lane][8] (2 MB)     [R12-validated layout]
//   t<16384 : out_lad = 0
//   t<8192  : Aext[l][i][part][r32] = packed (w1t,b1) bf16 hi/lo pairs
//   t<4096  : C0[row] = W2*w1t
//   t<64    : Jc[l] = sum_h W2*w1t
__global__ __launch_bounds__(256)
void conv_w1(const float* __restrict__ W1g, const float* __restrict__ b1g,
             const float* __restrict__ W2g,
             unsigned short* __restrict__ W1f, unsigned int* __restrict__ Aext,
             float* __restrict__ C0, float* __restrict__ Jc,
             float* __restrict__ out_lad) {
    const int t = blockIdx.x * 256 + threadIdx.x;   // 0..131071
    if (t < NTOT) out_lad[t] = 0.f;
    if (t < 4096) C0[t] = W2g[t] * W1g[(size_t)t * IN_DIM + 128];
    if (t < 64) {
        float s = 0.f;
        for (int h = 0; h < 64; ++h) {
            const int row = t * 64 + h;
            s += W2g[row] * W1g[(size_t)row * IN_DIM + 128];
        }
        Jc[t] = s;
    }
    if (t < 8192) {   // Aext: r32=t&31, part=(t>>5)&1, i=(t>>6)&1, l=t>>7
        const int r32p = t & 31, partp = (t >> 5) & 1;
        const int ip = (t >> 6) & 1, lp = t >> 7;
        const int row = lp * 64 + ip * 32 + r32p;
        unsigned short wh, wl, bh, bl;
        bsplit(W1g[(size_t)row * IN_DIM + 128], wh, wl);
        bsplit(b1g[row], bh, bl);
        Aext[t] = partp ? ((unsigned int)wl | ((unsigned int)bl << 16))
                        : ((unsigned int)wh | ((unsigned int)bh << 16));
    }
    // W1f fragment slot (validated layout)
    const int lane = t & 63;
    const int part = (t >> 6) & 1;
    const int ks   = (t >> 7) & 7;
    const int i    = (t >> 10) & 1;
    const int l    = t >> 11;                       // 0..63
    const int hi32 = lane >> 5, r32 = lane & 31;
    const int row  = l * 64 + i * 32 + r32;         // <= 4095
    const int k0   = ks * 16 + hi32 * 8;            // <= 120
    const float* src = W1g + (size_t)row * IN_DIM + k0;
    US8 v;
    #pragma unroll
    for (int e = 0; e < 8; ++e) {
        unsigned short h, lo;
        bsplit(src[e], h, lo);
        v.s[e] = part ? lo : h;
    }
    *reinterpret_cast<US8*>(W1f + (size_t)t * 8) = v;
}

// 256 thr / 4 waves; block = one 32-row n-tile x 16 latents (4 quad-iters).
// K=144 fused MFMA (b1 + xt*w1t as 9th K-step). x staged once; barrier-free
// quad loop; A from L2. grid 2048 = 512 tiles x 4 latent quarters.
__global__ __launch_bounds__(256, 4)
void fused_mfma(const float* __restrict__ xg,
                const float* __restrict__ W2g, const float* __restrict__ b2g,
                const unsigned short* __restrict__ W1f,
                const unsigned int* __restrict__ Aext,
                const float* __restrict__ C0, const float* __restrict__ Jc,
                float* __restrict__ out_res, float* __restrict__ out_lad)
{
    __shared__ unsigned short sXh[34][72];   // x hi, stride 144B
    __shared__ unsigned short sXl[34][72];   // x lo
    __shared__ float sJ[32][4];              // per-wn jacobian logs

    const int tid  = threadIdx.x;
    const int tile = blockIdx.x & 511;       // 0..511 : 32-row n-tile
    const int lq   = blockIdx.x >> 9;        // 0..3   : latent quarter
    const int pt   = tile >> 4;              // batch row
    const int s    = tile & 15;
    const size_t xrow0 = (size_t)pt * TROWS + s * 32;
    const size_t nbase = (size_t)tile * 32;

    // ---- stage x tile once: 34 rows x 64, bf16 hi/lo ----
    for (int i = tid; i < 34 * 16; i += 256) {
        const int row = i >> 4, c4 = (i & 15) << 2;
        const float4 v = *reinterpret_cast<const float4*>(
            xg + (xrow0 + row) * LATENT + c4);
        unsigned short h0,h1,h2,h3, l0,l1,l2,l3;
        bsplit(v.x, h0, l0); bsplit(v.y, h1, l1);
        bsplit(v.z, h2, l2); bsplit(v.w, h3, l3);
        *reinterpret_cast<US4*>(&sXh[row][c4]) = US4{h0, h1, h2, h3};
        *reinterpret_cast<US4*>(&sXl[row][c4]) = US4{l0, l1, l2, l3};
    }
    __syncthreads();   // single barrier; LDS read-only afterwards

    const int wn   = tid >> 6;               // 0..3
    const int lane = tid & 63;
    const int r32  = lane & 31;
    const int hi32 = lane >> 5;

    float jlog = 0.f, jprod = 1.f;

    #pragma unroll 1
    for (int q = 0; q < 4; ++q) {
        const int l = lq * 16 + q * 4 + wn;
        const unsigned short* A0 = W1f + (size_t)l * 16384 + (size_t)lane * 8;

        f32x16 acc[2];
        #pragma unroll
        for (int i = 0; i < 2; ++i)
            #pragma unroll
            for (int r = 0; r < 16; ++r) acc[i][r] = 0.f;

        // ---- K loop (k=0..127): A = W1 fragments (L2), B = x rows (LDS) ----
        #pragma unroll
        for (int ks = 0; ks < 8; ++ks) {
            const int lag = ks >> 2;
            const int cc  = (ks & 3) * 16 + hi32 * 8;
            const unsigned short* p0 = A0 + ks * 1024;
            bf16x8 awh[2], awl[2];
            #pragma unroll
            for (int i = 0; i < 2; ++i) {
                awh[i] = *reinterpret_cast<const bf16x8*>(p0 + i * 8192);
                awl[i] = *reinterpret_cast<const bf16x8*>(p0 + i * 8192 + 512);
            }
            const bf16x8 bxh = *reinterpret_cast<const bf16x8*>(&sXh[r32 + lag][cc]);
            const bf16x8 bxl = *reinterpret_cast<const bf16x8*>(&sXl[r32 + lag][cc]);
            #pragma unroll
            for (int i = 0; i < 2; ++i) {
                acc[i] = __builtin_amdgcn_mfma_f32_32x32x16_bf16(awh[i], bxh, acc[i], 0, 0, 0);
                acc[i] = __builtin_amdgcn_mfma_f32_32x32x16_bf16(awh[i], bxl, acc[i], 0, 0, 0);
                acc[i] = __builtin_amdgcn_mfma_f32_32x32x16_bf16(awl[i], bxh, acc[i], 0, 0, 0);
            }
        }

        // ---- 9th K-step: pre += xt*w1t + b1 (A=[w1t,b1], B=[xt,1]) ----
        {
            const int abase = l * 128 + r32;
            const unsigned int avh0 = Aext[abase];        // i=0 hi
            const unsigned int avl0 = Aext[abase + 32];   // i=0 lo
            const unsigned int avh1 = Aext[abase + 64];   // i=1 hi
            const unsigned int avl1 = Aext[abase + 96];   // i=1 lo
            const unsigned short xh = sXh[2 + r32][l];
            const unsigned short xl = sXl[2 + r32][l];
            bf16x8 aeh0 = {0,0,0,0,0,0,0,0}, ael0 = {0,0,0,0,0,0,0,0};
            bf16x8 aeh1 = {0,0,0,0,0,0,0,0}, ael1 = {0,0,0,0,0,0,0,0};
            bf16x8 beh  = {0,0,0,0,0,0,0,0}, bel  = {0,0,0,0,0,0,0,0};
            if (hi32 == 0) {   // k-cols/rows 0..7 carry the data; 8..15 zero
                aeh0[0] = (short)(avh0 & 0xffff); aeh0[1] = (short)(avh0 >> 16);
                ael0[0] = (short)(avl0 & 0xffff); ael0[1] = (short)(avl0 >> 16);
                aeh1[0] = (short)(avh1 & 0xffff); aeh1[1] = (short)(avh1 >> 16);
                ael1[0] = (short)(avl1 & 0xffff); ael1[1] = (short)(avl1 >> 16);
                beh[0] = (short)xh; beh[1] = (short)0x3F80;   // [xt_hi, 1.0]
                bel[0] = (short)xl;                            // [xt_lo, 0 ]
            }
            acc[0] = __builtin_amdgcn_mfma_f32_32x32x16_bf16(aeh0, beh, acc[0], 0, 0, 0);
            acc[0] = __builtin_amdgcn_mfma_f32_32x32x16_bf16(aeh0, bel, acc[0], 0, 0, 0);
            acc[0] = __builtin_amdgcn_mfma_f32_32x32x16_bf16(ael0, beh, acc[0], 0, 0, 0);
            acc[1] = __builtin_amdgcn_mfma_f32_32x32x16_bf16(aeh1, beh, acc[1], 0, 0, 0);
            acc[1] = __builtin_amdgcn_mfma_f32_32x32x16_bf16(aeh1, bel, acc[1], 0, 0, 0);
            acc[1] = __builtin_amdgcn_mfma_f32_32x32x16_bf16(ael1, beh, acc[1], 0, 0, 0);
        }

        // ---- epilogue: pre is complete in acc; h = i*32 + hi32*4 + g*8 + m ----
        float res0 = 0.f, jp0 = 0.f;
        #pragma unroll
        for (int i = 0; i < 2; ++i)
            #pragma unroll
            for (int g = 0; g < 4; ++g) {
                const int h0 = l * HID + i * 32 + hi32 * 4 + g * 8;
                const f32x4 w2 = *reinterpret_cast<const f32x4*>(W2g + h0);
                const f32x4 c0 = *reinterpret_cast<const f32x4*>(C0 + h0);
                #pragma unroll
                for (int m = 0; m < 4; ++m) {
                    const float pre = acc[i][g * 4 + m];
                    res0 += w2[m] * fmaxf(pre, SLOPE * pre);
                    jp0  += (pre >= 0.f) ? c0[m] : 0.f;
                }
            }

        res0 += __shfl_xor(res0, 32);
        jp0  += __shfl_xor(jp0, 32);
        const float jac = SLOPE * Jc[l] + (1.f - SLOPE) * jp0;

        if (hi32 == 0)
            out_res[(nbase + r32) * LATENT + l] = res0 + b2g[l];
        jprod *= jac;
    }

    jlog = logf(fabsf(jprod));
    if (hi32 == 0) sJ[r32][wn] = jlog;
    __syncthreads();
    if (tid < 32) {
        const float part = sJ[tid][0] + sJ[tid][1] + sJ[tid][2] + sJ[tid][3];
        atomicAdd(&out_lad[nbase + tid], part);
    }
}

extern "C" void kernel_launch(void* const* d_in, const int* in_sizes, int n_in,
                              void* d_out, int out_size, void* d_ws, size_t ws_size,
                              hipStream_t stream) {
    const float* xg  = (const float*)d_in[0];
    const float* W1g = (const float*)d_in[1];
    const float* b1g = (const float*)d_in[2];
    const float* W2g = (const float*)d_in[3];
    const float* b2g = (const float*)d_in[4];

    float* out_res = (float*)d_out;
    float* out_lad = out_res + (size_t)NTOT * LATENT;

    // ws layout (2.05 MB total, within proven budget):
    float*          C0   = (float*)d_ws;                    // 16 KB
    float*          Jc   = C0 + 4096;                       // 256 B
    unsigned int*   Aext = (unsigned int*)(Jc + 64);        // 32 KB
    unsigned short* W1f  = (unsigned short*)(Aext + 8192);  // 2 MB

    conv_w1<<<512, 256, 0, stream>>>(W1g, b1g, W2g, W1f, Aext, C0, Jc, out_lad);

    dim3 grid(2048);  // 512 n-tiles x 4 latent quarters
    fused_mfma<<<grid, 256, 0, stream>>>(xg, W2g, b2g, W1f, Aext, C0, Jc,
                                         out_res, out_lad);
}